// Round 9
// baseline (107.937 us; speedup 1.0000x reference)
//
#include <hip/hip_runtime.h>
#include <math.h>

// Problem constants (fixed by reference)
#define BATCH 2
#define SEQ   1024
#define DM    1024   // D_MODEL
#define MMEM  128    // memory slots
#define MEMD  512    // MEM_DIM
#define RELH  512    // REL_HID
#define KVLD  2560   // ld of combined [keys|values|m_part]
#define QLD   1536   // ld of combined [queries|q_part]

typedef _Float16 f16;
typedef __attribute__((ext_vector_type(2))) _Float16 f16x2;
typedef __attribute__((ext_vector_type(4))) _Float16 f16x4;
typedef __attribute__((ext_vector_type(8))) _Float16 f16x8;
typedef __attribute__((ext_vector_type(4))) float    f32x4;

__device__ inline float dot2acc(f16x2 a, f16x2 b, float c) {
#if __has_builtin(__builtin_amdgcn_fdot2)
    return __builtin_amdgcn_fdot2(a, b, c, false);
#else
    return c + (float)a[0] * (float)b[0] + (float)a[1] * (float)b[1];
#endif
}
__device__ inline f16x2 relu2(f16x2 a) {
    f16x2 z = { (_Float16)0.0f, (_Float16)0.0f };
#if __has_builtin(__builtin_elementwise_max)
    return __builtin_elementwise_max(a, z);
#else
    f16x2 r;
    r[0] = a[0] > z[0] ? a[0] : z[0];
    r[1] = a[1] > z[1] ? a[1] : z[1];
    return r;
#endif
}

// async global->LDS, 16B per lane (wave-uniform LDS base + lane*16)
__device__ inline void llds16(const void* gp, void* lp) {
    __builtin_amdgcn_global_load_lds(
        (const __attribute__((address_space(1))) void*)gp,
        (__attribute__((address_space(3))) void*)lp,
        16, 0, 0);
}

__device__ inline void tr_tile(float (*t)[65], const float* __restrict__ in,
                               f16* __restrict__ out, int R, int C, int tile) {
    const int tid = threadIdx.x;
    const int ctiles = C >> 6;
    const int r0 = (tile / ctiles) * 64, c0 = (tile % ctiles) * 64;
    #pragma unroll
    for (int i = 0; i < 16; ++i) {
        int idx = tid + 256 * i;
        int r = idx >> 6, c = idx & 63;
        t[c][r] = in[(size_t)(r0 + r) * C + c0 + c];
    }
    __syncthreads();
    #pragma unroll
    for (int i = 0; i < 16; ++i) {
        int idx = tid + 256 * i;
        int ro = idx >> 6, co = idx & 63;
        out[(size_t)(c0 + ro) * R + r0 + co] = (f16)t[ro][co];
    }
}

// ---------------------------------------------------------------------------
// L1 prep: weight transposes + bias vectors only (casts folded into GEMMs).
// grid 961 x 256.
// ---------------------------------------------------------------------------
__global__ __launch_bounds__(256) void prep(
    const float* __restrict__ Wq, const float* __restrict__ Wk,
    const float* __restrict__ Wv, const float* __restrict__ Wo,
    const float* __restrict__ W1,
    const float* __restrict__ bq, const float* __restrict__ bk,
    const float* __restrict__ bv, const float* __restrict__ b1,
    f16* __restrict__ btbig, f16* __restrict__ btcomb,
    f16* __restrict__ Wo_t, f16* __restrict__ W1q_t,
    float* __restrict__ bcomb, float* __restrict__ bqcomb)
{
    __shared__ float t[64][65];
    const int bid = blockIdx.x, tid = threadIdx.x;

    if (bid < 256) {                          // Wq^T -> btbig rows [0,1024)
        tr_tile(t, Wq, btbig, 1024, 1024, bid);
    } else if (bid < 384) {                   // Wk^T -> btcomb rows [0,1024)
        tr_tile(t, Wk, btcomb, 512, 1024, bid - 256);
    } else if (bid < 512) {                   // Wv^T -> btcomb rows [1024,2048)
        tr_tile(t, Wv, btcomb + (size_t)1024 * 512, 512, 1024, bid - 384);
    } else if (bid < 768) {                   // Wo^T
        tr_tile(t, Wo, Wo_t, 1024, 1024, bid - 512);
    } else if (bid < 896) {                   // W1q^T
        tr_tile(t, W1, W1q_t, 1024, 512, bid - 768);
    } else if (bid < 960) {                   // W1m^T -> btcomb rows [2048,2560)
        tr_tile(t, W1 + (size_t)1024 * 512, btcomb + (size_t)2048 * 512,
                512, 512, bid - 896);
    } else {                                  // bias vectors
        #pragma unroll
        for (int j = 0; j < 10; ++j) {
            int g = tid + 256 * j;
            float v = (g < 1024) ? bk[g] : (g < 2048) ? bv[g - 1024] : b1[g - 2048];
            bcomb[g] = v;
        }
        #pragma unroll
        for (int j = 0; j < 4; ++j) {
            int g = tid + 256 * j;
            bqcomb[g] = bq[g];                // cols [0,1024) of qcat bias
        }
    }
}

// ---------------------------------------------------------------------------
// MFMA GEMM core: C(f32,opt)/C2(f16,opt) = A @ Bt^T + bias.
// BM in {64,128}, BN=128, BK=64, 256 thr = 4 waves, double-buffered LDS.
// Per operand: CASTx=false -> f16 source staged via global_load_lds (inverse-
// swizzled source, linear LDS); CASTx=true -> f32 source, reg-staged with
// T14 split (load-early / cvt+ds_write-late), same XOR-swizzled LDS layout:
// LDS[row][slot s] = global[row][chunk s ^ (row&7)], chunk = 8 f16.
// ---------------------------------------------------------------------------
template<int BM, int BN, bool CASTA, bool CASTB>
__device__ __forceinline__ void gemm_core(
    const f16* __restrict__ Ah, const float* __restrict__ Af,
    const f16* __restrict__ Bth, const float* __restrict__ Btf,
    const float* __restrict__ bias, float* __restrict__ C,
    f16* __restrict__ C2, int K, int ldc, int lda, int ldb,
    int bx, int by, f16* Al, f16* Bl)
{
    constexpr int MF   = BM / 16;     // m-fragments
    constexpr int NF   = BN / 64;     // n-fragments per wave
    constexpr int ABUF = BM * 64;     // f16 per A buffer
    constexpr int BBUF = BN * 64;
    const int tid = threadIdx.x, lane = tid & 63, wid = tid >> 6;
    const size_t row0 = (size_t)by * BM;
    const size_t col0 = (size_t)bx * BN;
    const int lrow = lane >> 3;
    const int lcs  = (lane & 7) ^ lrow;       // inverse-swizzled source chunk
    const int r15 = lane & 15, l4 = lane >> 4;
    const int crow = tid >> 2, ckc = tid & 3; // cast-stage mapping

    f32x4 acc[MF][NF];
    #pragma unroll
    for (int m = 0; m < MF; ++m)
        #pragma unroll
        for (int n = 0; n < NF; ++n) acc[m][n] = (f32x4){0.f, 0.f, 0.f, 0.f};

    float4 aregs[CASTA ? (BM / 64) : 1][4];
    float4 bregs[CASTB ? (BN / 64) : 1][4];

    auto LOAD_A = [&](int kt) {
        if constexpr (CASTA) {
            #pragma unroll
            for (int g = 0; g < BM / 64; ++g) {
                const float* src = Af + (row0 + g * 64 + crow) * (size_t)lda
                                      + kt * 64 + ckc * 16;
                #pragma unroll
                for (int q = 0; q < 4; ++q) aregs[g][q] = *(const float4*)(src + q * 4);
            }
        }
    };
    auto LOAD_B = [&](int kt) {
        if constexpr (CASTB) {
            #pragma unroll
            for (int g = 0; g < BN / 64; ++g) {
                const float* src = Btf + (col0 + g * 64 + crow) * (size_t)ldb
                                       + kt * 64 + ckc * 16;
                #pragma unroll
                for (int q = 0; q < 4; ++q) bregs[g][q] = *(const float4*)(src + q * 4);
            }
        }
    };
    auto WRITE_A = [&](int buf) {
        if constexpr (CASTA) {
            #pragma unroll
            for (int g = 0; g < BM / 64; ++g) {
                const int row = g * 64 + crow;
                f16x8 h0 = { (f16)aregs[g][0].x, (f16)aregs[g][0].y,
                             (f16)aregs[g][0].z, (f16)aregs[g][0].w,
                             (f16)aregs[g][1].x, (f16)aregs[g][1].y,
                             (f16)aregs[g][1].z, (f16)aregs[g][1].w };
                f16x8 h1 = { (f16)aregs[g][2].x, (f16)aregs[g][2].y,
                             (f16)aregs[g][2].z, (f16)aregs[g][2].w,
                             (f16)aregs[g][3].x, (f16)aregs[g][3].y,
                             (f16)aregs[g][3].z, (f16)aregs[g][3].w };
                f16* base = Al + buf * ABUF + row * 64;
                *(f16x8*)(base + (((ckc * 2 + 0) ^ (row & 7)) * 8)) = h0;
                *(f16x8*)(base + (((ckc * 2 + 1) ^ (row & 7)) * 8)) = h1;
            }
        }
    };
    auto WRITE_B = [&](int buf) {
        if constexpr (CASTB) {
            #pragma unroll
            for (int g = 0; g < BN / 64; ++g) {
                const int row = g * 64 + crow;
                f16x8 h0 = { (f16)bregs[g][0].x, (f16)bregs[g][0].y,
                             (f16)bregs[g][0].z, (f16)bregs[g][0].w,
                             (f16)bregs[g][1].x, (f16)bregs[g][1].y,
                             (f16)bregs[g][1].z, (f16)bregs[g][1].w };
                f16x8 h1 = { (f16)bregs[g][2].x, (f16)bregs[g][2].y,
                             (f16)bregs[g][2].z, (f16)bregs[g][2].w,
                             (f16)bregs[g][3].x, (f16)bregs[g][3].y,
                             (f16)bregs[g][3].z, (f16)bregs[g][3].w };
                f16* base = Bl + buf * BBUF + row * 64;
                *(f16x8*)(base + (((ckc * 2 + 0) ^ (row & 7)) * 8)) = h0;
                *(f16x8*)(base + (((ckc * 2 + 1) ^ (row & 7)) * 8)) = h1;
            }
        }
    };
    auto STAGE_A16 = [&](int buf, int kt) {
        if constexpr (!CASTA) {
            const f16* Ab = Ah + row0 * lda + (size_t)kt * 64;
            #pragma unroll
            for (int j = 0; j < BM / 32; ++j) {
                const int c = wid * (BM / 32) + j;
                llds16(Ab + (size_t)(c * 8 + lrow) * lda + lcs * 8,
                       Al + buf * ABUF + c * 512);
            }
        }
    };
    auto STAGE_B16 = [&](int buf, int kt) {
        if constexpr (!CASTB) {
            const f16* Bb = Bth + col0 * ldb + (size_t)kt * 64;
            #pragma unroll
            for (int j = 0; j < BN / 32; ++j) {
                const int c = wid * (BN / 32) + j;
                llds16(Bb + (size_t)(c * 8 + lrow) * ldb + lcs * 8,
                       Bl + buf * BBUF + c * 512);
            }
        }
    };

    // prologue: stage k-tile 0
    LOAD_A(0); LOAD_B(0);
    STAGE_A16(0, 0); STAGE_B16(0, 0);
    WRITE_A(0); WRITE_B(0);
    __syncthreads();

    const int nk = K >> 6;
    int cur = 0;
    for (int kt = 0; kt < nk; ++kt) {
        const bool more = (kt + 1 < nk);
        if (more) {
            STAGE_A16(cur ^ 1, kt + 1);
            STAGE_B16(cur ^ 1, kt + 1);
            LOAD_A(kt + 1);
            LOAD_B(kt + 1);
        }
        #pragma unroll
        for (int kk = 0; kk < 2; ++kk) {
            f16x8 af[MF], bfr[NF];
            #pragma unroll
            for (int m = 0; m < MF; ++m) {
                const int rowA = m * 16 + r15;
                af[m] = *(const f16x8*)(Al + cur * ABUF + rowA * 64 +
                                        (((kk * 4 + l4) ^ (r15 & 7)) * 8));
            }
            #pragma unroll
            for (int n = 0; n < NF; ++n) {
                const int rowB = wid * (BN / 4) + n * 16 + r15;
                bfr[n] = *(const f16x8*)(Bl + cur * BBUF + rowB * 64 +
                                         (((kk * 4 + l4) ^ (r15 & 7)) * 8));
            }
            #pragma unroll
            for (int m = 0; m < MF; ++m)
                #pragma unroll
                for (int n = 0; n < NF; ++n)
                    acc[m][n] = __builtin_amdgcn_mfma_f32_16x16x32_f16(
                        af[m], bfr[n], acc[m][n], 0, 0, 0);
        }
        if (more) { WRITE_A(cur ^ 1); WRITE_B(cur ^ 1); }
        __syncthreads();
        cur ^= 1;
    }

    // C/D layout: col = lane&15, row = (lane>>4)*4 + j
    const int cr = l4, cc = r15;
    #pragma unroll
    for (int n = 0; n < NF; ++n) {
        const size_t col = col0 + wid * (BN / 4) + n * 16 + cc;
        const float bvv = bias ? bias[col] : 0.f;
        #pragma unroll
        for (int m = 0; m < MF; ++m) {
            #pragma unroll
            for (int j = 0; j < 4; ++j) {
                const size_t row = row0 + m * 16 + cr * 4 + j;
                const float v = acc[m][n][j] + bvv;
                if (C)  C[row * ldc + col] = v;
                if (C2) C2[row * ldc + col] = (f16)v;
            }
        }
    }
}

// ---------------------------------------------------------------------------
// L2: batched small GEMMs + bias-combine. grid 145 x 256.
//   [0,80)   kvm = mem(f32) @ [Wk|Wv|W1m] + [bk|bv|b1]   (CASTA)
//   [80,144) wq1t = W1q_t @ Wq(f32)^T                    (CASTB)
//   144      bqcomb[1024..1536) = bq @ W1q
// ---------------------------------------------------------------------------
__global__ __launch_bounds__(256) void smallgemms(
    const float* __restrict__ mem, const f16* __restrict__ btcomb,
    const float* __restrict__ bcomb, f16* __restrict__ kvm,
    const f16* __restrict__ W1q_t, const float* __restrict__ Wq,
    f16* __restrict__ wq1t, const float* __restrict__ bq,
    float* __restrict__ bqcomb)
{
    __shared__ __align__(16) char smem[49152];
    f16* Al = (f16*)smem;               // 16 KB (BM=64 dbuf)
    f16* Bl = (f16*)(smem + 16384);     // 32 KB (BN=128 dbuf)
    const int bid = blockIdx.x;

    if (bid < 80) {
        gemm_core<64, 128, true, false>(
            nullptr, mem, btcomb, nullptr, bcomb, nullptr, kvm,
            MEMD, KVLD, MEMD, MEMD, bid % 20, bid / 20, Al, Bl);
    } else if (bid < 144) {
        const int i = bid - 80;
        gemm_core<64, 128, false, true>(
            W1q_t, nullptr, nullptr, Wq, nullptr, nullptr, wq1t,
            DM, DM, DM, DM, i % 8, i / 8, Al, Bl);
    } else {
        float* bqs = (float*)smem;
        const int tid = threadIdx.x;
        #pragma unroll
        for (int j = 0; j < 4; ++j) bqs[tid + 256 * j] = bq[tid + 256 * j];
        __syncthreads();
        #pragma unroll
        for (int rr = 0; rr < 2; ++rr) {
            const int j = tid + rr * 256;
            float acc = 0.f;
            for (int k8 = 0; k8 < 128; ++k8) {
                f16x8 wv = *(const f16x8*)(W1q_t + (size_t)j * 1024 + k8 * 8);
                #pragma unroll
                for (int e = 0; e < 8; ++e) acc += bqs[k8 * 8 + e] * (float)wv[e];
            }
            bqcomb[1024 + j] = acc;
        }
    }
}

// ---------------------------------------------------------------------------
// L3: qcat GEMM 128x128 tiles (192) + VoT GEMM (32) + mpt (8). grid 232 x 256.
// Dynamic LDS 64 KB.
// ---------------------------------------------------------------------------
__global__ __launch_bounds__(256) void biggemm(
    const float* __restrict__ hs, const f16* __restrict__ btbig,
    const float* __restrict__ bqcomb, f16* __restrict__ qcat,
    const f16* __restrict__ kvm, const f16* __restrict__ Wo_t,
    f16* __restrict__ VoT, f16* __restrict__ mpt)
{
    extern __shared__ __align__(16) char smem[];
    const int bid = blockIdx.x, tid = threadIdx.x;

    if (bid < 192) {
        // qcat = hs(f32) @ btbig^T + bqcomb ; BM=128: Al 32K, Bl 32K
        gemm_core<128, 128, true, false>(
            nullptr, hs, btbig, nullptr, bqcomb, nullptr, qcat,
            DM, QLD, DM, DM, bid % 12, bid / 12,
            (f16*)smem, (f16*)(smem + 32768));
        return;
    }
    if (bid < 224) {
        // VoT = Wo_t @ values^T (values = kvm cols [1024,2048), +bv folded)
        const int i = bid - 192;
        gemm_core<64, 128, false, false>(
            Wo_t, nullptr, kvm + 1024, nullptr, nullptr, nullptr, VoT,
            DM, 256, DM, KVLD, i % 2, i / 2,
            (f16*)smem, (f16*)(smem + 16384));
        return;
    }
    // mpt: m_part rows (kvm cols 2048..2560) -> [b][256 h2][128 m][2]
    f16 (*t2)[136] = (f16(*)[136])smem;
    const f16* mpart = kvm + 2048;
    const int mb = bid - 224, b = mb >> 2, hc = mb & 3;
    #pragma unroll
    for (int k = 0; k < 8; ++k) {
        int idx = tid + 256 * k;
        int m = idx >> 4, hq = idx & 15;
        *(f16x8*)(&t2[m][hq * 8]) =
            *(const f16x8*)(mpart + (size_t)(b * 128 + m) * KVLD + hc * 128 + hq * 8);
    }
    __syncthreads();
    #pragma unroll
    for (int k = 0; k < 32; ++k) {
        int idx = tid + 256 * k;
        int h2l = idx >> 7, m = idx & 127;
        f16x2 v = { t2[m][h2l * 2], t2[m][h2l * 2 + 1] };
        *(f16x2*)(mpt + ((size_t)b * 256 + hc * 64 + h2l) * 256 + m * 2) = v;
    }
}

// ---------------------------------------------------------------------------
// L4: fused relevance + scores + softmax + P@Vo + bo -> out (f32).
// grid 256 x 256 (8 s-rows/block). Verbatim from R8 (passing).
// ---------------------------------------------------------------------------
__global__ __launch_bounds__(256) void relattn(
    const f16* __restrict__ qcat,    // [2048][QLD]: queries | q_part
    const f16* __restrict__ kvm,     // [256][KVLD]: keys in cols [0,1024)
    const f16* __restrict__ VoT,     // [1024][256]
    const f16* __restrict__ mpt,     // [b][256 h2][128 m][2]
    const float* __restrict__ W2,    // [512]
    const float* __restrict__ b2,    // [1]
    const float* __restrict__ bo,    // [1024]
    float* __restrict__ out,         // [2048][1024] f32
    float* __restrict__ attn_w)      // [2048][128]
{
    __shared__ __align__(16) char u[41984];      // qs|mps|w2s  then  sc
    __shared__ float rel_s[1024];                // [8][128] persistent
    __shared__ f16 Ps[8 * 136];

    const int tid = threadIdx.x;
    const int b = blockIdx.x >> 7, st = blockIdx.x & 127;
    const size_t rowbase = (size_t)b * SEQ + st * 8;
    const int w = tid >> 6, lane = tid & 63;
    const int l15 = lane & 15, l4 = lane >> 4;

    // ---------------- Phase R: relevance -> rel_s ----------------
    {
        f16* qs  = (f16*)u;                 // [8][512]  8 KB
        f16* mps = (f16*)(u + 8192);        // [64][256] 32 KB
        f16* w2s = (f16*)(u + 40960);       // [512]     1 KB

        {
            int r = tid >> 5, c = tid & 31;
            const f16* src = qcat + (rowbase + r) * QLD + 1024 + c * 16;
            *(f16x8*)(qs + r * 512 + c * 16)     = *(const f16x8*)(src);
            *(f16x8*)(qs + r * 512 + c * 16 + 8) = *(const f16x8*)(src + 8);
        }
        if (tid < 128) {
            float4 w4 = *(const float4*)(W2 + tid * 4);
            f16x4 hv = { (f16)w4.x, (f16)w4.y, (f16)w4.z, (f16)w4.w };
            *(f16x4*)(w2s + tid * 4) = hv;
        }
        const float b2v = b2[0];
        const int sg = w;

        float acc00 = 0.f, acc01 = 0.f, acc10 = 0.f, acc11 = 0.f;
        const f16* mptb = mpt + (size_t)b * 65536;

        for (int hc = 0; hc < 4; ++hc) {
            __syncthreads();
            {
                const f16x8* src = (const f16x8*)(mptb + hc * 16384);
                f16x8* dst = (f16x8*)mps;
                #pragma unroll
                for (int k = 0; k < 8; ++k) dst[tid + 256 * k] = src[tid + 256 * k];
            }
            __syncthreads();

            #pragma unroll 4
            for (int step = 0; step < 16; ++step) {
                const int habs = hc * 128 + step * 8;
                uint4 q0u = *(const uint4*)(qs + (2 * sg) * 512 + habs);
                uint4 q1u = *(const uint4*)(qs + (2 * sg + 1) * 512 + habs);
                uint4 wu  = *(const uint4*)(w2s + habs);
                const unsigned* q0p = (const unsigned*)&q0u;
                const unsigned* q1p = (const unsigned*)&q1u;
                const unsigned* wp_ = (const unsigned*)&wu;
                #pragma unroll
                for (int jj = 0; jj < 4; ++jj) {
                    uint2 mpu = *(const uint2*)(mps + ((step * 4 + jj) * 128 + 2 * lane) * 2);
                    f16x2 m0 = __builtin_bit_cast(f16x2, mpu.x);
                    f16x2 m1 = __builtin_bit_cast(f16x2, mpu.y);
                    f16x2 wp = __builtin_bit_cast(f16x2, wp_[jj]);
                    f16x2 q0 = __builtin_bit_cast(f16x2, q0p[jj]);
                    f16x2 q1 = __builtin_bit_cast(f16x2, q1p[jj]);
                    acc00 = dot2acc(relu2(q0 + m0), wp, acc00);
                    acc01 = dot2acc(relu2(q0 + m1), wp, acc01);
                    acc10 = dot2acc(relu2(q1 + m0), wp, acc10);
                    acc11 = dot2acc(relu2(q1 + m1), wp, acc11);
                }
            }
        }

        rel_s[(2 * sg) * 128 + 2 * lane]         = 1.f / (1.f + __expf(-(acc00 + b2v)));
        rel_s[(2 * sg) * 128 + 2 * lane + 1]     = 1.f / (1.f + __expf(-(acc01 + b2v)));
        rel_s[(2 * sg + 1) * 128 + 2 * lane]     = 1.f / (1.f + __expf(-(acc10 + b2v)));
        rel_s[(2 * sg + 1) * 128 + 2 * lane + 1] = 1.f / (1.f + __expf(-(acc11 + b2v)));
    }
    __syncthreads();   // rel_s ready; qs/mps dead -> sc may overwrite

    float* sc = (float*)u;   // [4][16][128] 32 KB

    // ---------------- Phase S: QK^T partials over k-quarter ----------------
    {
        f32x4 aq[8];
        #pragma unroll
        for (int n = 0; n < 8; ++n) aq[n] = (f32x4){0.f, 0.f, 0.f, 0.f};
        #pragma unroll
        for (int k4 = 0; k4 < 8; ++k4) {
            const int k0 = w * 256 + k4 * 32 + l4 * 8;
            f16x8 af = *(const f16x8*)(qcat + (rowbase + (l15 & 7)) * QLD + k0);
            #pragma unroll
            for (int n = 0; n < 8; ++n) {
                f16x8 bf = *(const f16x8*)(kvm + (size_t)(b * 128 + n * 16 + l15) * KVLD + k0);
                aq[n] = __builtin_amdgcn_mfma_f32_16x16x32_f16(af, bf, aq[n], 0, 0, 0);
            }
        }
        #pragma unroll
        for (int n = 0; n < 8; ++n)
            #pragma unroll
            for (int j = 0; j < 4; ++j)
                sc[(w * 16 + l4 * 4 + j) * 128 + n * 16 + l15] = aq[n][j];
    }
    __syncthreads();

    // ---------------- reduce partials, *rel/32, softmax ----------------
    {
        const int r = tid >> 5, seg = tid & 31;
        float4 xs = {0.f, 0.f, 0.f, 0.f};
        #pragma unroll
        for (int ww = 0; ww < 4; ++ww) {
            float4 p = *(const float4*)(sc + (ww * 16 + r) * 128 + seg * 4);
            xs.x += p.x; xs.y += p.y; xs.z += p.z; xs.w += p.w;
        }
        float4 rl = *(const float4*)(rel_s + r * 128 + seg * 4);
        float x[4];
        x[0] = xs.x * 0.03125f * rl.x; x[1] = xs.y * 0.03125f * rl.y;
        x[2] = xs.z * 0.03125f * rl.z; x[3] = xs.w * 0.03125f * rl.w;
        float mx = fmaxf(fmaxf(x[0], x[1]), fmaxf(x[2], x[3]));
        #pragma unroll
        for (int d = 1; d < 32; d <<= 1) mx = fmaxf(mx, __shfl_xor(mx, d));
        float ss = 0.f;
        #pragma unroll
        for (int c = 0; c < 4; ++c) { x[c] = __expf(x[c] - mx); ss += x[c]; }
        #pragma unroll
        for (int d = 1; d < 32; d <<= 1) ss += __shfl_xor(ss, d);
        const float inv = 1.f / ss;
        #pragma unroll
        for (int c = 0; c < 4; ++c) x[c] *= inv;
        float4 o = { x[0], x[1], x[2], x[3] };
        *(float4*)(attn_w + (rowbase + r) * 128 + seg * 4) = o;
        f16x4 ph = { (f16)x[0], (f16)x[1], (f16)x[2], (f16)x[3] };
        *(f16x4*)(Ps + r * 136 + seg * 4) = ph;
    }
    __syncthreads();

    // ---------------- Phase P: out = P @ Vo + bo over d-quarter ----------------
    {
        f16x8 pa[4];
        #pragma unroll
        for (int k = 0; k < 4; ++k)
            pa[k] = *(const f16x8*)(Ps + (l15 & 7) * 136 + k * 32 + l4 * 8);
        #pragma unroll
        for (int n2 = 0; n2 < 16; ++n2) {
            f32x4 ac = (f32x4){0.f, 0.f, 0.f, 0.f};
            const int d0 = w * 256 + n2 * 16;
            #pragma unroll
            for (int k = 0; k < 4; ++k) {
                f16x8 bf = *(const f16x8*)(VoT + (size_t)(d0 + l15) * 256 + b * 128 + k * 32 + l4 * 8);
                ac = __builtin_amdgcn_mfma_f32_16x16x32_f16(pa[k], bf, ac, 0, 0, 0);
            }
            if (l4 < 2) {
                const float bov = bo[d0 + l15];
                #pragma unroll
                for (int j = 0; j < 4; ++j)
                    out[(rowbase + l4 * 4 + j) * 1024 + d0 + l15] = ac[j] + bov;
            }
        }
    }
}

// ---------------------------------------------------------------------------
extern "C" void kernel_launch(void* const* d_in, const int* in_sizes, int n_in,
                              void* d_out, int out_size, void* d_ws, size_t ws_size,
                              hipStream_t stream)
{
    const float* hs  = (const float*)d_in[0];
    const float* mem = (const float*)d_in[1];
    const float* Wq  = (const float*)d_in[2];
    const float* bq  = (const float*)d_in[3];
    const float* Wk  = (const float*)d_in[4];
    const float* bk  = (const float*)d_in[5];
    const float* Wv  = (const float*)d_in[6];
    const float* bv  = (const float*)d_in[7];
    const float* Wo  = (const float*)d_in[8];
    const float* bo  = (const float*)d_in[9];
    const float* W1  = (const float*)d_in[10];  // (1536,512)
    const float* b1  = (const float*)d_in[11];
    const float* W2  = (const float*)d_in[12];
    const float* b2  = (const float*)d_in[13];

    float* out   = (float*)d_out;                       // (2,1024,1024)
    float* attnw = out + (size_t)BATCH * SEQ * DM;      // (2,1024,128)

    // workspace layout (16B-aligned, ~17 MB)
    char* wp = (char*)d_ws;
    f16* btbig   = (f16*)wp;  wp += (size_t)QLD * DM * 2;             // 3 MB
    f16* btcomb  = (f16*)wp;  wp += (size_t)KVLD * MEMD * 2;          // 2.5 MB
    f16* Wo_t    = (f16*)wp;  wp += (size_t)DM * DM * 2;              // 2 MB
    f16* W1q_t   = (f16*)wp;  wp += (size_t)RELH * DM * 2;            // 1 MB
    f16* qcat    = (f16*)wp;  wp += (size_t)BATCH * SEQ * QLD * 2;    // 6 MB
    f16* kvm     = (f16*)wp;  wp += (size_t)BATCH * MMEM * KVLD * 2;  // 1.25 MB
    f16* VoT     = (f16*)wp;  wp += (size_t)DM * BATCH * MMEM * 2;    // 0.5 MB
    f16* mpt     = (f16*)wp;  wp += (size_t)BATCH * MMEM * RELH * 2;  // 0.25 MB
    float* bcomb = (float*)wp; wp += (size_t)KVLD * 4;
    float* bqcomb= (float*)wp; wp += (size_t)QLD * 4;

    dim3 blk(256);

    // L1: weight transposes + biases (casts folded into GEMM staging)
    prep<<<dim3(961), blk, 0, stream>>>(
        Wq, Wk, Wv, Wo, W1, bq, bk, bv, b1,
        btbig, btcomb, Wo_t, W1q_t, bcomb, bqcomb);

    // L2: kvm GEMM (mem f32 A-cast) + wq1t GEMM (Wq f32 B-cast) + bias-combine
    smallgemms<<<dim3(145), blk, 0, stream>>>(
        mem, btcomb, bcomb, kvm,
        W1q_t, Wq, btbig + (size_t)1024 * DM, bq, bqcomb);

    // L3: qcat GEMM (hs f32 A-cast, 128x128 tiles) + VoT GEMM + mpt
    biggemm<<<dim3(232), blk, 65536, stream>>>(
        hs, btbig, bqcomb, qcat, kvm, Wo_t, VoT, mpt);

    // L4: fused relevance + attention -> out, attn_w
    relattn<<<dim3(256), blk, 0, stream>>>(
        qcat, kvm, VoT, mpt, W2, b2, bo, out, attnw);
}